// Round 20
// baseline (97.162 us; speedup 1.0000x reference)
//
#include <hip/hip_runtime.h>
#include <hip/hip_bf16.h>

#define N_ 4096
#define D_ 768
#define NCLS 128
#define BM 128
#define BN 128
#define NG 96     // k-groups of 8 per row
#define NSTEP 24  // K32 MFMA steps

typedef __bf16 bf16x8 __attribute__((ext_vector_type(8)));
typedef float f32x4 __attribute__((ext_vector_type(4)));

// Normalize both matrices, writing bf16 output in MFMA FRAGMENT ORDER:
// ushort idx(r,k) = ((r>>4)*NG + (k>>3))*128 + (r&15)*8 + (k&7).
// One wave per row (4 rows/block); block 0 zeroes reduce accumulators.
__global__ __launch_bounds__(256) void normalize_kernel(
    const float* __restrict__ img, const float* __restrict__ txt,
    unsigned short* __restrict__ img_f, unsigned short* __restrict__ txt_f,
    double* __restrict__ accs, unsigned* __restrict__ cnt) {
  if (blockIdx.x == 0 && threadIdx.x == 0) {
    accs[0] = 0.0;
    accs[1] = 0.0;
    *cnt = 0u;
  }
  int idx = blockIdx.x * 4 + (threadIdx.x >> 6);  // row 0..8191
  int lane = threadIdx.x & 63;
  const float* s;
  unsigned short* d;
  if (idx < N_) {
    s = img + (size_t)idx * D_;
    d = img_f;
  } else {
    s = txt + (size_t)(idx - N_) * D_;
    d = txt_f;
    idx -= N_;
  }
  float4 v0 = ((const float4*)s)[lane];
  float4 v1 = ((const float4*)s)[lane + 64];
  float4 v2 = ((const float4*)s)[lane + 128];
  float ss = v0.x * v0.x + v0.y * v0.y + v0.z * v0.z + v0.w * v0.w +
             v1.x * v1.x + v1.y * v1.y + v1.z * v1.z + v1.w * v1.w +
             v2.x * v2.x + v2.y * v2.y + v2.z * v2.z + v2.w * v2.w;
#pragma unroll
  for (int m = 32; m; m >>= 1) ss += __shfl_xor(ss, m);
  float inv = 1.0f / fmaxf(sqrtf(ss), 1e-8f);
  const int tb = (idx >> 4) * NG, fo = (idx & 15) * 8;  // row-tile, fr offset
#pragma unroll
  for (int p = 0; p < 3; ++p) {
    float4 v = (p == 0) ? v0 : (p == 1) ? v1 : v2;
    int k = 4 * lane + p * 256;
    ushort4 o;
    o.x = __bfloat16_as_ushort(__float2bfloat16(v.x * inv));
    o.y = __bfloat16_as_ushort(__float2bfloat16(v.y * inv));
    o.z = __bfloat16_as_ushort(__float2bfloat16(v.z * inv));
    o.w = __bfloat16_as_ushort(__float2bfloat16(v.w * inv));
    *(ushort4*)&d[(size_t)(tb + (k >> 3)) * 128 + fo + (k & 7)] = o;
  }
}

// LDS-FREE 128x128-tile GEMM: fragments are coalesced global b128 loads from
// the pre-arranged layout (lane l reads base + (l>>4)*128 + (l&15)*16 --
// contiguous 512B per instruction, L2/L3-resident: 12.6MB total operands).
// No ds ops, no barriers in the main loop -- the compiler software-pipelines
// the 8 loads/step arbitrarily deep. 4 waves (2x2), 64x64/wave, acc[4][4].
// XCD column-stripe block swizzle keeps each XCD's 4 B-panels L2-hot.
__global__ __launch_bounds__(256) void gemm_epi_kernel(
    const unsigned short* __restrict__ Af, const unsigned short* __restrict__ Bf,
    const int* __restrict__ labels, float* __restrict__ row_part,
    float* __restrict__ col_part, float* __restrict__ S_part) {
  __shared__ int labR[BM], labC[BN];
  __shared__ float rbuf[2][BM], cbuf[2][BN];
  __shared__ float sbuf[4];

  // XCD-aware remap (bijective; grid 1024 % 8 == 0)
  const int lin = blockIdx.y * 32 + blockIdx.x;
  const int xcd = lin & 7, idx = lin >> 3;
  const int bx = xcd * 4 + (idx & 3), by = idx >> 2;

  const int tid = threadIdx.x;
  const int lane = tid & 63, wave = tid >> 6;
  const int wr = wave >> 1, wc = wave & 1;
  const int g = lane >> 4, fr = lane & 15;
  const int rowBase = by * BM, colBase = bx * BN;

  if (tid < BM) labR[tid] = labels[rowBase + tid];
  else labC[tid - BM] = labels[colBase + tid - BM];

  // fragment base pointers (ushort): tile T row-tiles, + (u*4+g)*128 + fr*8
  const unsigned short* pa[4];
  const unsigned short* pb[4];
#pragma unroll
  for (int m = 0; m < 4; ++m)
    pa[m] = Af + (size_t)((by * 8 + wr * 4 + m) * NG + g) * 128 + fr * 8;
#pragma unroll
  for (int n = 0; n < 4; ++n)
    pb[n] = Bf + (size_t)((bx * 8 + wc * 4 + n) * NG + g) * 128 + fr * 8;

  f32x4 acc[4][4] = {};

  for (int u = 0; u < NSTEP; ++u) {
    const int off = u * 512;  // 4 groups of 128 ushorts per K32-step
    bf16x8 af[4], bf[4];
#pragma unroll
    for (int m = 0; m < 4; ++m) af[m] = *(const bf16x8*)(pa[m] + off);
#pragma unroll
    for (int n = 0; n < 4; ++n) bf[n] = *(const bf16x8*)(pb[n] + off);
#pragma unroll
    for (int m = 0; m < 4; ++m)
#pragma unroll
      for (int n = 0; n < 4; ++n)
        acc[m][n] = __builtin_amdgcn_mfma_f32_16x16x32_bf16(af[m], bf[n], acc[m][n], 0, 0, 0);
  }
  __syncthreads();  // labR/labC visible (only barrier in the kernel body)

  const float scale = 14.285714285714286f;  // 1/0.07
  float sPart = 0.f;
  float colAcc[4] = {0.f, 0.f, 0.f, 0.f};
#pragma unroll
  for (int m = 0; m < 4; ++m) {
    float ra2[4] = {0.f, 0.f, 0.f, 0.f};
#pragma unroll
    for (int n = 0; n < 4; ++n) {
      int col = wc * 64 + n * 16 + fr;
      int lc = labC[col];
#pragma unroll
      for (int r = 0; r < 4; ++r) {
        float v = acc[m][n][r] * scale;
        float e = __expf(v);
        ra2[r] += e;
        colAcc[n] += e;
        int row = wr * 64 + m * 16 + g * 4 + r;
        if (labR[row] == lc) sPart += v;
      }
    }
#pragma unroll
    for (int r = 0; r < 4; ++r) {
      float x = ra2[r];
      x += __shfl_xor(x, 1);
      x += __shfl_xor(x, 2);
      x += __shfl_xor(x, 4);
      x += __shfl_xor(x, 8);
      if (fr == 0) rbuf[wc][wr * 64 + m * 16 + g * 4 + r] = x;
    }
  }
#pragma unroll
  for (int n = 0; n < 4; ++n) {
    float x = colAcc[n];
    x += __shfl_xor(x, 16);
    x += __shfl_xor(x, 32);
    if (g == 0) cbuf[wr][wc * 64 + n * 16 + fr] = x;
  }
  float s = sPart;
#pragma unroll
  for (int m = 32; m; m >>= 1) s += __shfl_xor(s, m);
  if (lane == 0) sbuf[wave] = s;
  __syncthreads();
  if (tid < BM)
    row_part[(size_t)bx * N_ + rowBase + tid] = rbuf[0][tid] + rbuf[1][tid];
  else
    col_part[(size_t)by * N_ + colBase + (tid - BM)] = cbuf[0][tid - BM] + cbuf[1][tid - BM];
  if (tid == 0) S_part[by * 32 + bx] = sbuf[0] + sbuf[1] + sbuf[2] + sbuf[3];
}

// Merged final reduction: per-block hist + partials -> device-scope double
// atomics; last-done block writes the scalar loss.
__global__ __launch_bounds__(256) void reduce_kernel(
    const float* __restrict__ row_part, const float* __restrict__ col_part,
    const float* __restrict__ S_part, const int* __restrict__ labels,
    double* __restrict__ accs, unsigned* __restrict__ cnt, float* __restrict__ out) {
  __shared__ int hist[NCLS];
  int tid = threadIdx.x;
  if (tid < NCLS) hist[tid] = 0;
  __syncthreads();
  for (int j = tid; j < N_; j += 256) atomicAdd(&hist[labels[j]], 1);
  __syncthreads();

  int i = blockIdx.x * 256 + tid;  // 0..4095
  float rs = 0.f, cs = 0.f;
#pragma unroll
  for (int b = 0; b < 32; ++b) {
    rs += row_part[(size_t)b * N_ + i];
    cs += col_part[(size_t)b * N_ + i];
  }
  int c = hist[labels[i]];
  double term = (double)c * ((double)logf(rs) + (double)logf(cs));
  double sterm = (i < 1024) ? (double)S_part[i] : 0.0;
#pragma unroll
  for (int m = 32; m; m >>= 1) {
    term += __shfl_xor(term, m);
    sterm += __shfl_xor(sterm, m);
  }
  __shared__ double tbuf[4], sb[4];
  int lane = tid & 63, w = tid >> 6;
  if (lane == 0) { tbuf[w] = term; sb[w] = sterm; }
  __syncthreads();
  if (tid == 0) {
    atomicAdd(&accs[0], tbuf[0] + tbuf[1] + tbuf[2] + tbuf[3]);
    atomicAdd(&accs[1], sb[0] + sb[1] + sb[2] + sb[3]);
    __threadfence();
    unsigned old = atomicAdd(cnt, 1u);
    if (old == 15u) {
      double t = atomicAdd(&accs[0], 0.0);
      double s2 = atomicAdd(&accs[1], 0.0);
      out[0] = (float)((t - 2.0 * s2) / (2.0 * (double)N_));
    }
  }
}

extern "C" void kernel_launch(void* const* d_in, const int* in_sizes, int n_in,
                              void* d_out, int out_size, void* d_ws, size_t ws_size,
                              hipStream_t stream) {
  const float* img = (const float*)d_in[0];
  const float* txt = (const float*)d_in[1];
  const int* labels = (const int*)d_in[2];
  float* out = (float*)d_out;
  char* ws = (char*)d_ws;

  // workspace layout (bytes)
  unsigned short* img_f = (unsigned short*)(ws);              //  6,291,456
  unsigned short* txt_f = (unsigned short*)(ws + 6291456);    //  6,291,456
  float* row_part = (float*)(ws + 12582912);                  //    524,288 (32 x 4096)
  float* col_part = (float*)(ws + 13107200);                  //    524,288
  float* S_part = (float*)(ws + 13631488);                    //      4,096
  double* accs = (double*)(ws + 13635584);                    //  16 (+cnt 4)
  unsigned* cnt = (unsigned*)(ws + 13635600);

  normalize_kernel<<<2 * N_ / 4, 256, 0, stream>>>(img, txt, img_f, txt_f, accs, cnt);
  gemm_epi_kernel<<<dim3(32, 32), 256, 0, stream>>>(
      img_f, txt_f, labels, row_part, col_part, S_part);
  reduce_kernel<<<16, 256, 0, stream>>>(row_part, col_part, S_part, labels, accs, cnt, out);
}

// Round 21
// 46.187 us; speedup vs baseline: 2.1037x; 2.1037x over previous
//
#include <hip/hip_runtime.h>
#include <hip/hip_bf16.h>

#define N_ 4096
#define D_ 768
#define NCLS 128
#define BM 128
#define BN 128
#define BKB 128   // fp8 elems (=bytes) per K-step
#define NSTEP 6   // D_/BKB

typedef float f32x4 __attribute__((ext_vector_type(4)));
typedef long lng2 __attribute__((ext_vector_type(2)));

#define SBAR() asm volatile("s_barrier" ::: "memory")
#define VMWAIT8() asm volatile("s_waitcnt vmcnt(8)" ::: "memory")
#define LGKM0() asm volatile("s_waitcnt lgkmcnt(0)" ::: "memory")

__device__ __forceinline__ void gload16(const unsigned char* g, unsigned char* l) {
  __builtin_amdgcn_global_load_lds(
      (const __attribute__((address_space(1))) unsigned int*)g,
      (__attribute__((address_space(3))) unsigned int*)l, 16, 0, 0);
}

// Normalize to fp8 e4m3, k-PERMUTED within each 128B segment so GEMM fragment
// reads are b128: byte pos in segment = (g*2 + (ks>>1))*16 + (ks&1)*8 + j for
// original k = ks*32 + g*8 + j. 192 thr x 4 elems -> one int store each.
// Block 0 zeroes reduce accumulators.
__global__ __launch_bounds__(192) void normalize_kernel(
    const float* __restrict__ img, const float* __restrict__ txt,
    unsigned char* __restrict__ img_f8, unsigned char* __restrict__ txt_f8,
    double* __restrict__ accs, unsigned* __restrict__ cnt) {
  int b = blockIdx.x;
  if (b == 0 && threadIdx.x == 0) {
    accs[0] = 0.0;
    accs[1] = 0.0;
    *cnt = 0u;
  }
  const float* s;
  unsigned char* d;
  if (b < N_) {
    s = img + (size_t)b * D_;
    d = img_f8 + (size_t)b * D_;
  } else {
    s = txt + (size_t)(b - N_) * D_;
    d = txt_f8 + (size_t)(b - N_) * D_;
  }
  int tid = threadIdx.x;
  float4 v = ((const float4*)s)[tid];
  float ss = v.x * v.x + v.y * v.y + v.z * v.z + v.w * v.w;
#pragma unroll
  for (int m = 32; m; m >>= 1) ss += __shfl_xor(ss, m);
  __shared__ float wsum[3];
  int lane = tid & 63, w = tid >> 6;
  if (lane == 0) wsum[w] = ss;
  __syncthreads();
  float inv = 1.0f / fmaxf(sqrtf(wsum[0] + wsum[1] + wsum[2]), 1e-8f);
  int r = 0;
  r = __builtin_amdgcn_cvt_pk_fp8_f32(v.x * inv, v.y * inv, r, false);
  r = __builtin_amdgcn_cvt_pk_fp8_f32(v.z * inv, v.w * inv, r, true);
  const int k0 = tid * 4;
  const int seg = k0 >> 7, ko = k0 & 127;
  const int ks = ko >> 5, gg = (ko >> 3) & 3, h = (ko >> 2) & 1;
  ((int*)d)[seg * 32 + (gg * 2 + (ks >> 1)) * 4 + (ks & 1) * 2 + h] = r;
}

// 128x128-tile fp8 GEMM: BK=128 -> 6 K-steps (half of bf16's 12 barriers,
// half the staged bytes; fp8 MFMA = bf16 rate). b128 LDS ops on BOTH sides
// (r9/r10's 3.1M conflicts were the b64 ops): staging = r16's exact machinery
// (gload_lds, source chunk pre-swizzled (l&7)^(row&7), linear dest, 2-slot
// ring, raw s_barrier + counted vmcnt(8)); fragment read = ds_read_b128 at
// slot (g*2+p)^(row&7) giving granules (g,2p),(g,2p+1) -- r7's measured-0
// pattern. Per step/wave: 16 b128 reads + 64 MFMA. XCD block remap.
__global__ __launch_bounds__(256) void gemm_epi_kernel(
    const unsigned char* __restrict__ A, const unsigned char* __restrict__ B,
    const int* __restrict__ labels, float* __restrict__ row_part,
    float* __restrict__ col_part, float* __restrict__ S_part) {
  __shared__ __align__(16) unsigned char As[2][16384];  // [slot][row][128B]
  __shared__ __align__(16) unsigned char Bs[2][16384];
  __shared__ int labR[BM], labC[BN];
  __shared__ float rbuf[2][BM], cbuf[2][BN];
  __shared__ float sbuf[4];

  // XCD-aware remap (bijective; grid 1024 % 8 == 0)
  const int lin = blockIdx.y * 32 + blockIdx.x;
  const int xcd = lin & 7, idx = lin >> 3;
  const int bx = xcd * 4 + (idx & 3), by = idx >> 2;

  const int tid = threadIdx.x;
  const int lane = tid & 63, wave = tid >> 6;
  const int wr = wave >> 1, wc = wave & 1;
  const int g = lane >> 4, fr = lane & 15;
  const int rowBase = by * BM, colBase = bx * BN;

  if (tid < BM) labR[tid] = labels[rowBase + tid];
  else labC[tid - BM] = labels[colBase + tid - BM];
  __syncthreads();  // labels visible before any gload issue

  // staging: wave w, issue j covers rows j*32 + w*8 + (lane>>3);
  // source 16B chunk pre-swizzled (l&7)^(row&7); linear LDS dest.
  const int r0 = lane >> 3;
  const int cswz = (lane & 7) ^ (r0 & 7);
  const unsigned char* pa = A + (size_t)(rowBase + wave * 8 + r0) * D_ + cswz * 16;
  const unsigned char* pb = B + (size_t)(colBase + wave * 8 + r0) * D_ + cswz * 16;
  const int dbase = wave * 1024;  // bytes; + j*4096

  // prologue: issue step 0 into slot 0 (8 loads in flight)
#pragma unroll
  for (int j = 0; j < 4; ++j) {
    gload16(pa + (size_t)(32 * j) * D_, &As[0][dbase + j * 4096]);
    gload16(pb + (size_t)(32 * j) * D_, &Bs[0][dbase + j * 4096]);
  }

  f32x4 acc[4][4] = {};

  for (int u = 0; u < NSTEP; ++u) {
    SBAR();  // all waves done reading the slot about to be overwritten
    {
      const int su = (u + 1 < NSTEP) ? u + 1 : u;  // tail: restage dead slot
      const size_t kk = (size_t)su * BKB;
      const int sl = (u + 1) & 1;
#pragma unroll
      for (int j = 0; j < 4; ++j) {
        gload16(pa + (size_t)(32 * j) * D_ + kk, &As[sl][dbase + j * 4096]);
        gload16(pb + (size_t)(32 * j) * D_ + kk, &Bs[sl][dbase + j * 4096]);
      }
    }
    VMWAIT8();  // my step-u loads landed; step-u+1's 8 stay in flight
    SBAR();     // every wave's step-u loads landed: slot u&1 fully valid
    const unsigned char* as_ = As[u & 1];
    const unsigned char* bs_ = Bs[u & 1];
#pragma unroll
    for (int p = 0; p < 2; ++p) {  // k-slice pairs (ks=2p, 2p+1)
      const int gp = g * 2 + p;
      lng2 bq[4];
#pragma unroll
      for (int n = 0; n < 4; ++n) {
        const int row = wc * 64 + n * 16 + fr;
        bq[n] = *(const lng2*)&bs_[row * 128 + (gp ^ (fr & 7)) * 16];
      }
#pragma unroll
      for (int m = 0; m < 4; ++m) {
        const int row = wr * 64 + m * 16 + fr;
        lng2 aq = *(const lng2*)&as_[row * 128 + (gp ^ (fr & 7)) * 16];
#pragma unroll
        for (int n = 0; n < 4; ++n) {
          acc[m][n] = __builtin_amdgcn_mfma_f32_16x16x32_fp8_fp8(aq[0], bq[n][0], acc[m][n], 0, 0, 0);
          acc[m][n] = __builtin_amdgcn_mfma_f32_16x16x32_fp8_fp8(aq[1], bq[n][1], acc[m][n], 0, 0, 0);
        }
      }
    }
    LGKM0();  // my ds_reads drained before signaling the next top barrier
  }
  __syncthreads();  // full drain before epilogue

  const float scale = 14.285714285714286f;  // 1/0.07
  float sPart = 0.f;
  float colAcc[4] = {0.f, 0.f, 0.f, 0.f};
#pragma unroll
  for (int m = 0; m < 4; ++m) {
    float ra2[4] = {0.f, 0.f, 0.f, 0.f};
#pragma unroll
    for (int n = 0; n < 4; ++n) {
      int col = wc * 64 + n * 16 + fr;
      int lc = labC[col];
#pragma unroll
      for (int r = 0; r < 4; ++r) {
        float v = acc[m][n][r] * scale;
        float e = __expf(v);
        ra2[r] += e;
        colAcc[n] += e;
        int row = wr * 64 + m * 16 + g * 4 + r;
        if (labR[row] == lc) sPart += v;
      }
    }
#pragma unroll
    for (int r = 0; r < 4; ++r) {
      float x = ra2[r];
      x += __shfl_xor(x, 1);
      x += __shfl_xor(x, 2);
      x += __shfl_xor(x, 4);
      x += __shfl_xor(x, 8);
      if (fr == 0) rbuf[wc][wr * 64 + m * 16 + g * 4 + r] = x;
    }
  }
#pragma unroll
  for (int n = 0; n < 4; ++n) {
    float x = colAcc[n];
    x += __shfl_xor(x, 16);
    x += __shfl_xor(x, 32);
    if (g == 0) cbuf[wr][wc * 64 + n * 16 + fr] = x;
  }
  float s = sPart;
#pragma unroll
  for (int m = 32; m; m >>= 1) s += __shfl_xor(s, m);
  if (lane == 0) sbuf[wave] = s;
  __syncthreads();
  if (tid < BM)
    row_part[(size_t)bx * N_ + rowBase + tid] = rbuf[0][tid] + rbuf[1][tid];
  else
    col_part[(size_t)by * N_ + colBase + (tid - BM)] = cbuf[0][tid - BM] + cbuf[1][tid - BM];
  if (tid == 0) S_part[by * 32 + bx] = sbuf[0] + sbuf[1] + sbuf[2] + sbuf[3];
}

// Merged final reduction: per-block hist + partials -> device-scope double
// atomics; last-done block writes the scalar loss.
__global__ __launch_bounds__(256) void reduce_kernel(
    const float* __restrict__ row_part, const float* __restrict__ col_part,
    const float* __restrict__ S_part, const int* __restrict__ labels,
    double* __restrict__ accs, unsigned* __restrict__ cnt, float* __restrict__ out) {
  __shared__ int hist[NCLS];
  int tid = threadIdx.x;
  if (tid < NCLS) hist[tid] = 0;
  __syncthreads();
  for (int j = tid; j < N_; j += 256) atomicAdd(&hist[labels[j]], 1);
  __syncthreads();

  int i = blockIdx.x * 256 + tid;  // 0..4095
  float rs = 0.f, cs = 0.f;
#pragma unroll
  for (int b = 0; b < 32; ++b) {
    rs += row_part[(size_t)b * N_ + i];
    cs += col_part[(size_t)b * N_ + i];
  }
  int c = hist[labels[i]];
  double term = (double)c * ((double)logf(rs) + (double)logf(cs));
  double sterm = (i < 1024) ? (double)S_part[i] : 0.0;
#pragma unroll
  for (int m = 32; m; m >>= 1) {
    term += __shfl_xor(term, m);
    sterm += __shfl_xor(sterm, m);
  }
  __shared__ double tbuf[4], sb[4];
  int lane = tid & 63, w = tid >> 6;
  if (lane == 0) { tbuf[w] = term; sb[w] = sterm; }
  __syncthreads();
  if (tid == 0) {
    atomicAdd(&accs[0], tbuf[0] + tbuf[1] + tbuf[2] + tbuf[3]);
    atomicAdd(&accs[1], sb[0] + sb[1] + sb[2] + sb[3]);
    __threadfence();
    unsigned old = atomicAdd(cnt, 1u);
    if (old == 15u) {
      double t = atomicAdd(&accs[0], 0.0);
      double s2 = atomicAdd(&accs[1], 0.0);
      out[0] = (float)((t - 2.0 * s2) / (2.0 * (double)N_));
    }
  }
}

extern "C" void kernel_launch(void* const* d_in, const int* in_sizes, int n_in,
                              void* d_out, int out_size, void* d_ws, size_t ws_size,
                              hipStream_t stream) {
  const float* img = (const float*)d_in[0];
  const float* txt = (const float*)d_in[1];
  const int* labels = (const int*)d_in[2];
  float* out = (float*)d_out;
  char* ws = (char*)d_ws;

  // workspace layout (bytes)
  unsigned char* img_f8 = (unsigned char*)(ws);            //  3,145,728
  unsigned char* txt_f8 = (unsigned char*)(ws + 3145728);  //  3,145,728
  float* row_part = (float*)(ws + 6291456);                //    524,288 (32 x 4096)
  float* col_part = (float*)(ws + 6815744);                //    524,288
  float* S_part = (float*)(ws + 7340032);                  //      4,096
  double* accs = (double*)(ws + 7344128);                  //  16 (+cnt 4)
  unsigned* cnt = (unsigned*)(ws + 7344144);

  normalize_kernel<<<2 * N_, 192, 0, stream>>>(img, txt, img_f8, txt_f8, accs, cnt);
  gemm_epi_kernel<<<dim3(32, 32), 256, 0, stream>>>(
      img_f8, txt_f8, labels, row_part, col_part, S_part);
  reduce_kernel<<<16, 256, 0, stream>>>(row_part, col_part, S_part, labels, accs, cnt, out);
}